// Round 8
// baseline (547.024 us; speedup 1.0000x reference)
//
#include <hip/hip_runtime.h>
#include <hip/hip_bf16.h>

using bf16 = __hip_bfloat16;
typedef __attribute__((ext_vector_type(8))) short short8;
typedef __attribute__((ext_vector_type(4))) float f32x4;

__device__ __forceinline__ float b2f(bf16 v){ return __bfloat162float(v); }
__device__ __forceinline__ float sigf(float v){ return 1.f/(1.f + __expf(-v)); }
__device__ __forceinline__ float ldv(const float* p, int i){ return p[i]; }
__device__ __forceinline__ float ldv(const bf16* p, int i){ return b2f(p[i]); }
__device__ __forceinline__ void stv(float* p, int i, float v){ p[i] = v; }
__device__ __forceinline__ void stv(bf16* p, int i, float v){ p[i] = __float2bfloat16(v); }
__device__ __forceinline__ unsigned short f2h(float v){
  bf16 h = __float2bfloat16(v); return *(unsigned short*)&h;
}
__device__ __forceinline__ unsigned short ldh(const float* p, int i){ return f2h(p[i]); }
__device__ __forceinline__ unsigned short ldh(const bf16* p, int i){
  return *(const unsigned short*)(p + i);
}
// 8 bf16 from LDS: 4x ds_read_b32 at word stride S (k-pair layout)
__device__ __forceinline__ short8 ld8s(const unsigned int* p, int S){
  union { unsigned int u[4]; short8 s; } v;
  v.u[0] = p[0]; v.u[1] = p[S]; v.u[2] = p[2*S]; v.u[3] = p[3*S];
  return v.s;
}

// ---------------------------------------------------------------------------
// K0: dtype detect. flag=1 => inputs are f32.
// ---------------------------------------------------------------------------
__global__ __launch_bounds__(256) void k_detect(const unsigned short* xs, int* flag){
  __shared__ int cnt;
  if (threadIdx.x == 0) cnt = 0;
  __syncthreads();
  int local = 0;
  for (int i = threadIdx.x; i < 16384; i += 256){
    if (((xs[i] >> 7) & 0xFF) == 0xFF) local++;
  }
  if (local) atomicAdd(&cnt, local);
  __syncthreads();
  if (threadIdx.x == 0) *flag = (cnt > 0) ? 1 : 0;
}

// ---------------------------------------------------------------------------
// K0b: canonicalize params (unchanged from R7).
// ---------------------------------------------------------------------------
struct ParamSrc { const void* p[18]; };

__global__ __launch_bounds__(256) void k_convert(ParamSrc ps, const int* flagp,
    float* cpar, bf16* wdefb, bf16* woffb, bf16* wg1b, bf16* wcrossb, bf16* woutb){
  static constexpr int n[23]   = {41472,18,147456,131072,147456,64,64,64,64,64,
                                  16384,256,65536,256,256,256,256,256,
                                  147456,73728,147456,131072,65536};
  static constexpr int off[18] = {0,41472,41504,188960,320032,467488,467552,467616,
                                  467680,467744,467808,484192,484448,549984,550240,
                                  550496,550752,551008};
  const int s = blockIdx.y;
  const bool f32 = (*flagp != 0);
  if (s >= 18){
    static constexpr int srcs[5] = {2, 0, 4, 3, 12};
    const int src_slot = srcs[s - 18];
    bf16* dsts[5] = {wdefb, woffb, wg1b, wcrossb, woutb};
    bf16* dst = dsts[s - 18];
    const int nsrc = (s == 19) ? 41472 : n[s];
    if (f32){
      const float* src = (const float*)ps.p[src_slot];
      for (int i = blockIdx.x * 256 + threadIdx.x; i < n[s]; i += gridDim.x * 256)
        dst[i] = (i < nsrc) ? __float2bfloat16(src[i]) : __float2bfloat16(0.f);
    } else {
      const bf16* src = (const bf16*)ps.p[src_slot];
      for (int i = blockIdx.x * 256 + threadIdx.x; i < n[s]; i += gridDim.x * 256)
        dst[i] = (i < nsrc) ? src[i] : __float2bfloat16(0.f);
    }
    return;
  }
  float* dst = cpar + off[s];
  if (f32){
    const float* src = (const float*)ps.p[s];
    for (int i = blockIdx.x * 256 + threadIdx.x; i < n[s]; i += gridDim.x * 256)
      dst[i] = src[i];
  } else {
    const bf16* src = (const bf16*)ps.p[s];
    for (int i = blockIdx.x * 256 + threadIdx.x; i < n[s]; i += gridDim.x * 256)
      dst[i] = b2f(src[i]);
  }
}

// ---------------------------------------------------------------------------
// 3x3 pad=1 conv v4: block = 32-px half-row, grid 512 (b*128 + y*2 + half).
// LDS cols k-pair u32 [k2 row][stride 34]: writes are 32-lane full-bank runs
// (2-way uniform = free); reads row-step 4*34 = 136 = 8 mod 32 (2-way free).
// Wave = m-tile, 2 n-tiles per afr; 9 afr preloaded per chunk (batched L2
// latency). KSPLIT (coff): w&1 = m-tile, w>>1 = K-half, LDS reduction.
// ---------------------------------------------------------------------------
template<typename T, bool KSPLIT, bool EPI>
__device__ __forceinline__ void conv3v4_body(const T* __restrict__ xin,
    const bf16* __restrict__ wb, const float* __restrict__ cbv,
    const float* __restrict__ gam, const float* __restrict__ bet,
    const float* __restrict__ mea, const float* __restrict__ var,
    float* __restrict__ outp, int CO, unsigned int* cols32){
  const int bx = blockIdx.x;
  const int b = bx >> 7, y = (bx >> 1) & 63, half = bx & 1;
  const int px0 = half * 32;
  const int t = threadIdx.x;
  const int l = t & 63, w = t >> 6;
  const int lm = l & 15, lq = l >> 4;
  const int gpx = t & 31, gs = t >> 5;         // gather: 8 slots x 32 px
  const int mw = KSPLIT ? (w & 1) : w;
  f32x4 acc0 = {0.f,0.f,0.f,0.f}, acc1 = {0.f,0.f,0.f,0.f};
  const int xcol = px0 + gpx;

  for (int ci = 0; ci < 8; ci++){
    __syncthreads();
    // ---- gather: slot gs loads channels gs*4..+3 (2 channel-pairs)
    #pragma unroll
    for (int cp = 0; cp < 2; cp++){
      float v[18];
      #pragma unroll
      for (int cl = 0; cl < 2; cl++){
        const T* xc = xin + (b * 256 + ci * 32 + gs * 4 + cp * 2 + cl) * 4096;
        #pragma unroll
        for (int ti = 0; ti < 3; ti++){
          const int yy = y + ti - 1;
          const bool vy = (unsigned)yy < 64u;
          #pragma unroll
          for (int tj = 0; tj < 3; tj++){
            const int xc2 = xcol + tj - 1;
            v[cl * 9 + ti * 3 + tj] =
              (vy && (unsigned)xc2 < 64u) ? ldv(xc, yy * 64 + xc2) : 0.f;
          }
        }
      }
      const int kr = gs * 18 + cp * 9;
      #pragma unroll
      for (int i = 0; i < 9; i++)
        cols32[(kr + i) * 34 + gpx] =
          (unsigned int)f2h(v[2*i]) | ((unsigned int)f2h(v[2*i+1]) << 16);
    }
    __syncthreads();
    // ---- MFMA: preload 9 afr, then 9 ksteps x 2 n-tiles
    if (!KSPLIT || ((ci >> 2) == (w >> 1))){
      const bf16* arow = wb + (mw * 16 + lm) * 2304 + ci * 288 + lq * 8;
      short8 af[9];
      #pragma unroll
      for (int kk = 0; kk < 9; kk++) af[kk] = *(const short8*)(arow + kk * 32);
      #pragma unroll
      for (int kk = 0; kk < 9; kk++){
        const unsigned int* bp = cols32 + (kk * 16 + lq * 4) * 34 + lm;
        short8 b0 = ld8s(bp, 34);
        short8 b1 = ld8s(bp + 16, 34);
        acc0 = __builtin_amdgcn_mfma_f32_16x16x32_bf16(af[kk], b0, acc0, 0, 0, 0);
        acc1 = __builtin_amdgcn_mfma_f32_16x16x32_bf16(af[kk], b1, acc1, 0, 0, 0);
      }
    }
  }
  if constexpr (KSPLIT){
    __syncthreads();
    float* red = (float*)cols32;
    if (w >= 2){
      #pragma unroll
      for (int r = 0; r < 4; r++){
        red[(w - 2) * 512 + l * 8 + r]     = acc0[r];
        red[(w - 2) * 512 + l * 8 + 4 + r] = acc1[r];
      }
    }
    __syncthreads();
    if (w >= 2) return;
    #pragma unroll
    for (int r = 0; r < 4; r++){
      acc0[r] += red[w * 512 + l * 8 + r];
      acc1[r] += red[w * 512 + l * 8 + 4 + r];
    }
  }
  const int pxb = y * 64 + px0;
  #pragma unroll
  for (int nn = 0; nn < 2; nn++){
    const f32x4& a = nn ? acc1 : acc0;
    #pragma unroll
    for (int r = 0; r < 4; r++){
      const int co = mw * 16 + lq * 4 + r;
      if (co >= CO) continue;
      float v = a[r] + cbv[co];
      if constexpr (EPI){
        float inv = gam[co] * rsqrtf(var[co] + 1e-5f);
        v = v * inv + (bet[co] - mea[co] * inv);
        v = v * sigf(v);
      }
      outp[(b * CO + co) * 4096 + pxb + nn * 16 + lm] = v;
    }
  }
}

__global__ __launch_bounds__(256) void k_coff2(const void* x, const int* flagp,
    const bf16* woffb, const float* cb, float* offc){
  __shared__ __align__(16) unsigned int cols32[144 * 34];
  if (*flagp) conv3v4_body<float, true, false>((const float*)x, woffb, cb,
                  nullptr, nullptr, nullptr, nullptr, offc, 18, cols32);
  else        conv3v4_body<bf16, true, false>((const bf16*)x, woffb, cb,
                  nullptr, nullptr, nullptr, nullptr, offc, 18, cols32);
}

__global__ __launch_bounds__(256) void k_g12(const float* xdense,
    const bf16* wg1b, const float* cb, const float* gam, const float* bet,
    const float* mea, const float* var, float* abuf){
  __shared__ __align__(16) unsigned int cols32[144 * 34];
  conv3v4_body<float, false, true>(xdense, wg1b, cb, gam, bet, mea, var,
                                   abuf, 64, cols32);
}

// ---------------------------------------------------------------------------
// K2a: deform gather -> global cols (unchanged from R7).
// ---------------------------------------------------------------------------
template<typename T>
__device__ __forceinline__ void dgath_body(const T* __restrict__ x,
    const float* __restrict__ offc, int g, unsigned short* __restrict__ colsg){
  const int strip = blockIdx.x, cs = blockIdx.y;
  const int b = strip >> 4;
  const int p = (strip & 15) * 256 + threadIdx.x;
  const int pg = b * 4096 + p;
  const int y = p >> 6, xx = p & 63;
  const float* ob = offc + b * 18 * 4096 + p;
  const T* xgb = x + (b * 256 + g * 64 + cs * 4) * 4096;
  #pragma unroll
  for (int tap = 0; tap < 9; tap++){
    float dy = ob[(2*tap)*4096], dx = ob[(2*tap+1)*4096];
    float py  = (float)(y + tap/3 - 1) + dy;
    float pxf = (float)(xx + tap%3 - 1) + dx;
    float y0f = floorf(py), x0f = floorf(pxf);
    int y0 = (int)y0f, x0 = (int)x0f;
    float wy1 = py - y0f, wx1 = pxf - x0f;
    float wy0 = 1.f - wy1, wx0 = 1.f - wx1;
    bool vy0 = (unsigned)y0 < 64u, vy1 = (unsigned)(y0+1) < 64u;
    bool vx0 = (unsigned)x0 < 64u, vx1 = (unsigned)(x0+1) < 64u;
    float w00 = (vy0 && vx0) ? wy0*wx0 : 0.f;
    float w01 = (vy0 && vx1) ? wy0*wx1 : 0.f;
    float w10 = (vy1 && vx0) ? wy1*wx0 : 0.f;
    float w11 = (vy1 && vx1) ? wy1*wx1 : 0.f;
    int yc0 = min(max(y0,0),63),   yc1 = min(max(y0+1,0),63);
    int xc0 = min(max(x0,0),63),   xc1 = min(max(x0+1,0),63);
    int i00 = yc0*64+xc0, i01 = yc0*64+xc1, i10 = yc1*64+xc0, i11 = yc1*64+xc1;
    #pragma unroll
    for (int c = 0; c < 4; c++){
      const T* xc = xgb + c * 4096;
      float val = w00*ldv(xc,i00) + w01*ldv(xc,i01)
                + w10*ldv(xc,i10) + w11*ldv(xc,i11);
      colsg[((cs*4 + c)*9 + tap)*16384 + pg] = f2h(val);
    }
  }
}

__global__ __launch_bounds__(256) void k_dgath(const void* x, const int* flagp,
    const float* offc, int g, unsigned short* colsg){
  if (*flagp) dgath_body((const float*)x, offc, g, colsg);
  else        dgath_body((const bf16*)x, offc, g, colsg);
}

// ---------------------------------------------------------------------------
// K2b: deform GEMM v2: M=64, N=32/block (grid 512), K=576 in 9 chunks of 64.
// bt [32 k2][34] u32: stage slots sk=2w+sq (bank shift 16 -> 2-way free);
// reads 4*34 = 8 mod 32 (free). Wave = m-tile; afr reused across 2 n-tiles.
// ---------------------------------------------------------------------------
__global__ __launch_bounds__(256) void k_dgemm(const unsigned short* __restrict__ colsg,
    const bf16* __restrict__ wdefb, int g, unsigned short* __restrict__ xdirb){
  __shared__ __align__(16) unsigned int bt[32 * 34];
  const int n0 = blockIdx.x * 32;
  const int b = n0 >> 12, p0 = n0 & 4095;
  const int t = threadIdx.x;
  const int w = t >> 6, l = t & 63, lm = l & 15, lq = l >> 4;
  const int spx = t & 31, sk = 2 * w + (l >> 5);
  f32x4 acc0 = {0.f,0.f,0.f,0.f}, acc1 = {0.f,0.f,0.f,0.f};
  for (int ch = 0; ch < 9; ch++){
    __syncthreads();
    #pragma unroll
    for (int i = 0; i < 4; i++){
      const int k2 = sk * 4 + i;
      const int k = ch * 64 + 2 * k2;
      unsigned int h0 = colsg[k * 16384 + n0 + spx];
      unsigned int h1 = colsg[(k + 1) * 16384 + n0 + spx];
      bt[k2 * 34 + spx] = h0 | (h1 << 16);
    }
    __syncthreads();
    const bf16* arow = wdefb + (g*64 + w*16 + lm)*576 + ch*64 + lq*8;
    short8 a0 = *(const short8*)(arow);
    short8 a1 = *(const short8*)(arow + 32);
    const unsigned int* bp0 = bt + (lq*4) * 34 + lm;
    const unsigned int* bp1 = bt + (16 + lq*4) * 34 + lm;
    acc0 = __builtin_amdgcn_mfma_f32_16x16x32_bf16(a0, ld8s(bp0, 34), acc0, 0, 0, 0);
    acc1 = __builtin_amdgcn_mfma_f32_16x16x32_bf16(a0, ld8s(bp0 + 16, 34), acc1, 0, 0, 0);
    acc0 = __builtin_amdgcn_mfma_f32_16x16x32_bf16(a1, ld8s(bp1, 34), acc0, 0, 0, 0);
    acc1 = __builtin_amdgcn_mfma_f32_16x16x32_bf16(a1, ld8s(bp1 + 16, 34), acc1, 0, 0, 0);
  }
  #pragma unroll
  for (int r = 0; r < 4; r++){
    const int row = (b*256 + g*64 + w*16 + lq*4 + r) * 4096 + p0 + lm;
    xdirb[row]      = f2h(acc0[r]);
    xdirb[row + 16] = f2h(acc1[r]);
  }
}

// ---------------------------------------------------------------------------
// K3: 1x1 conv concat([x_dir, x_prev]) * w_cross — MFMA GEMM v2.
// Wave = m-tile; afr reused across 4 n-tiles (4x fewer A-load stalls).
// ---------------------------------------------------------------------------
template<typename T>
__device__ __forceinline__ void cross_body(const unsigned short* __restrict__ xdirb,
    const T* __restrict__ xprev, const bf16* __restrict__ wcb,
    float* __restrict__ xdense, unsigned int* bt){
  const int bx = blockIdx.x;
  const int b = bx >> 6, p0 = (bx & 63) * 64;
  const int co0 = blockIdx.y * 64;
  const int t = threadIdx.x;
  const int w = t >> 6, l = t & 63, lm = l & 15, lq = l >> 4;
  const int spx = l;
  f32x4 acc[4];
  #pragma unroll
  for (int m = 0; m < 4; m++) acc[m] = (f32x4){0.f,0.f,0.f,0.f};
  for (int cc = 0; cc < 512; cc += 64){
    __syncthreads();
    #pragma unroll
    for (int i = 0; i < 8; i++){
      const int k2l = w * 8 + i;
      const int k = cc + 2 * k2l;
      unsigned int h0, h1;
      if (k < 256){
        h0 = xdirb[(b*256 + k)*4096 + p0 + spx];
        h1 = xdirb[(b*256 + k + 1)*4096 + p0 + spx];
      } else {
        h0 = ldh(xprev, (b*256 + k - 256)*4096 + p0 + spx);
        h1 = ldh(xprev, (b*256 + k - 255)*4096 + p0 + spx);
      }
      bt[k2l * 66 + spx] = h0 | (h1 << 16);
    }
    __syncthreads();
    #pragma unroll
    for (int ks = 0; ks < 2; ks++){
      short8 afr = *(const short8*)(wcb + (co0 + w*16 + lm)*512 + cc + ks*32 + lq*8);
      #pragma unroll
      for (int nn = 0; nn < 4; nn++){
        short8 bfr = ld8s(bt + (ks*16 + lq*4) * 66 + nn*16 + lm, 66);
        acc[nn] = __builtin_amdgcn_mfma_f32_16x16x32_bf16(afr, bfr, acc[nn], 0, 0, 0);
      }
    }
  }
  #pragma unroll
  for (int nn = 0; nn < 4; nn++){
    #pragma unroll
    for (int r = 0; r < 4; r++)
      xdense[(b*256 + co0 + w*16 + lq*4 + r)*4096 + p0 + nn*16 + lm] = acc[nn][r];
  }
}

__global__ __launch_bounds__(256) void k_cross_m(const unsigned short* xdirb,
    const void* xprev, const int* flagp, const bf16* wcb, float* xdense){
  __shared__ __align__(16) unsigned int bt[32 * 66];
  if (*flagp) cross_body(xdirb, (const float*)xprev, wcb, xdense, bt);
  else        cross_body(xdirb, (const bf16*)xprev, wcb, xdense, bt);
}

// ---------------------------------------------------------------------------
// K5: 1x1 conv 64->256 + bias + sigmoid, xab = bf16(xdense * attn). grid (64,16).
// ---------------------------------------------------------------------------
__global__ __launch_bounds__(256) void k_attn(
    const float* __restrict__ abuf, const float* __restrict__ cw,
    const float* __restrict__ cb, const float* __restrict__ xdense,
    unsigned short* __restrict__ xab){
  const int q0 = blockIdx.x * 256;
  const int b = q0 >> 12, p0 = q0 & 4095;
  const int co0 = blockIdx.y * 16;
  const int p = p0 + threadIdx.x;
  float acc[16];
  #pragma unroll
  for (int j = 0; j < 16; j++) acc[j] = 0.f;
  const float* ab = abuf + b * 64 * 4096;
  for (int c = 0; c < 64; c++){
    float av = ab[c * 4096 + p];
    #pragma unroll
    for (int j = 0; j < 16; j++) acc[j] += cw[(co0 + j) * 64 + c] * av;
  }
  #pragma unroll
  for (int j = 0; j < 16; j++){
    const int co = co0 + j;
    float attn = sigf(acc[j] + cb[co]);
    const int idx = (b * 256 + co) * 4096 + p;
    xab[idx] = f2h(xdense[idx] * attn);
  }
}

// ---------------------------------------------------------------------------
// K6: 1x1 conv 256->256 — MFMA GEMM v2 + bias + BN + SiLU + residual (dual).
// ---------------------------------------------------------------------------
template<typename T>
__device__ __forceinline__ void out_body(const unsigned short* __restrict__ xab,
    const bf16* __restrict__ wob, const float* __restrict__ cb,
    const float* __restrict__ gam, const float* __restrict__ bet,
    const float* __restrict__ mea, const float* __restrict__ var,
    const T* __restrict__ xres, T* __restrict__ out, unsigned int* bt){
  const int bx = blockIdx.x;
  const int b = bx >> 6, p0 = (bx & 63) * 64;
  const int co0 = blockIdx.y * 64;
  const int t = threadIdx.x;
  const int w = t >> 6, l = t & 63, lm = l & 15, lq = l >> 4;
  const int spx = l;
  f32x4 acc[4];
  #pragma unroll
  for (int m = 0; m < 4; m++) acc[m] = (f32x4){0.f,0.f,0.f,0.f};
  for (int cc = 0; cc < 256; cc += 64){
    __syncthreads();
    #pragma unroll
    for (int i = 0; i < 8; i++){
      const int k2l = w * 8 + i;
      const int k = cc + 2 * k2l;
      unsigned int h0 = xab[(b*256 + k)*4096 + p0 + spx];
      unsigned int h1 = xab[(b*256 + k + 1)*4096 + p0 + spx];
      bt[k2l * 66 + spx] = h0 | (h1 << 16);
    }
    __syncthreads();
    #pragma unroll
    for (int ks = 0; ks < 2; ks++){
      short8 afr = *(const short8*)(wob + (co0 + w*16 + lm)*256 + cc + ks*32 + lq*8);
      #pragma unroll
      for (int nn = 0; nn < 4; nn++){
        short8 bfr = ld8s(bt + (ks*16 + lq*4) * 66 + nn*16 + lm, 66);
        acc[nn] = __builtin_amdgcn_mfma_f32_16x16x32_bf16(afr, bfr, acc[nn], 0, 0, 0);
      }
    }
  }
  #pragma unroll
  for (int nn = 0; nn < 4; nn++){
    #pragma unroll
    for (int r = 0; r < 4; r++){
      const int co = co0 + w*16 + lq*4 + r;
      float v = acc[nn][r] + cb[co];
      float inv = gam[co] * rsqrtf(var[co] + 1e-5f);
      v = v * inv + (bet[co] - mea[co] * inv);
      v = v * sigf(v);
      const int idx = (b*256 + co)*4096 + p0 + nn*16 + lm;
      stv(out, idx, v + ldv(xres, idx));
    }
  }
}

__global__ __launch_bounds__(256) void k_out_m(const unsigned short* xab,
    const bf16* wob, const float* cb, const float* gam, const float* bet,
    const float* mea, const float* var, const void* xres, void* out,
    const int* flagp){
  __shared__ __align__(16) unsigned int bt[32 * 66];
  if (*flagp) out_body(xab, wob, cb, gam, bet, mea, var, (const float*)xres, (float*)out, bt);
  else        out_body(xab, wob, cb, gam, bet, mea, var, (const bf16*)xres, (bf16*)out, bt);
}

// ---------------------------------------------------------------------------
extern "C" void kernel_launch(void* const* d_in, const int* in_sizes, int n_in,
                              void* d_out, int out_size, void* d_ws, size_t ws_size,
                              hipStream_t stream) {
  const void* x      = d_in[0];
  const void* x_prev = d_in[1];

  float* ws   = (float*)d_ws;
  int*   flag = (int*)ws;                 // ws[0..15] reserved
  float* cpar = ws + 16;                  // canonical fp32 params (551264 f)
  float* cb_off   = cpar + 41472;
  float* cb_g1    = cpar + 467488;
  float* cg1_gam  = cpar + 467552;
  float* cg1_bet  = cpar + 467616;
  float* cg1_mea  = cpar + 467680;
  float* cg1_var  = cpar + 467744;
  float* cw_g2    = cpar + 467808;
  float* cb_g2    = cpar + 484192;
  float* cb_out   = cpar + 549984;
  float* co_gam   = cpar + 550240;
  float* co_bet   = cpar + 550496;
  float* co_mea   = cpar + 550752;
  float* co_var   = cpar + 551008;

  float* q = ws + 16 + 551264;
  bf16*  wdefb   = (bf16*)q;  q += 73728;   // 147456 bf16
  bf16*  woffb   = (bf16*)q;  q += 36864;   // 73728 bf16 (18->32 pad)
  bf16*  wg1b    = (bf16*)q;  q += 73728;   // 147456 bf16
  bf16*  wcrossb = (bf16*)q;  q += 65536;   // 131072 bf16
  bf16*  woutb   = (bf16*)q;  q += 32768;   // 65536 bf16
  float* offc    = q;         q += 294912;  // 4*18*4096 f32
  unsigned short* xdirb = (unsigned short*)q; q += 2097152; // 4*256*4096 bf16 (pad)
  float* xdense  = q;         q += 4194304; // 4*256*4096 f32
  float* abuf    = q;         q += 1048576; // 4*64*4096 f32
  unsigned short* xab = xdirb;              // reuse (xdirb dead after cross)
  unsigned short* colsg = (unsigned short*)xdense; // 18.9 MB aliases xdense+abuf

  ParamSrc ps;
  for (int i = 0; i < 18; i++) ps.p[i] = d_in[2 + i];

  k_detect<<<dim3(1), 256, 0, stream>>>((const unsigned short*)x, flag);
  k_convert<<<dim3(96, 23), 256, 0, stream>>>(ps, flag, cpar, wdefb, woffb,
                                              wg1b, wcrossb, woutb);
  k_coff2<<<dim3(512), 256, 0, stream>>>(x, flag, woffb, cb_off, offc);
  for (int g = 0; g < 4; g++){
    k_dgath<<<dim3(64, 16), 256, 0, stream>>>(x, flag, offc, g, colsg);
    k_dgemm<<<dim3(512), 256, 0, stream>>>(colsg, wdefb, g, xdirb);
  }
  k_cross_m<<<dim3(256, 4), 256, 0, stream>>>(xdirb, x_prev, flag, wcrossb, xdense);
  k_g12<<<dim3(512), 256, 0, stream>>>(xdense, wg1b, cb_g1, cg1_gam, cg1_bet,
                                       cg1_mea, cg1_var, abuf);
  k_attn<<<dim3(64, 16), 256, 0, stream>>>(abuf, cw_g2, cb_g2, xdense, xab);
  k_out_m<<<dim3(256, 4), 256, 0, stream>>>(xab, woutb, cb_out, co_gam, co_bet,
                                            co_mea, co_var, x, d_out, flag);
}